// Round 1
// baseline (15592.960 us; speedup 1.0000x reference)
//
#include <hip/hip_runtime.h>

// Round 1: correctness-first scalar fp32 LSTM stack.
// One wave (64 lanes) per batch element. Lane k (k<51) owns hidden unit k's
// 4 gate rows (i,f,g,o at rows k, 51+k, 102+k, 153+k). Broadcasts of h/c
// across lanes via __shfl; layer-4 (51 -> 4) contraction via __shfl_xor
// butterfly. Weights read directly from global (208 KB, L2/L3 resident).

constexpr int BATCH = 2048;
constexpr int T_STEPS = 256;
constexpr int H = 51;  // H1 == H2

__device__ __forceinline__ float frcp(float x) {
#if __has_builtin(__builtin_amdgcn_rcpf)
    return __builtin_amdgcn_rcpf(x);
#else
    return 1.0f / x;
#endif
}

__device__ __forceinline__ float sigmoid_f(float x) {
    // 1 / (1 + e^-x); exp(-x) overflows to +inf for very negative x -> rcp -> 0 (safe)
    float e = __expf(-x);
    return frcp(1.0f + e);
}

__device__ __forceinline__ float tanh_f(float x) {
    // tanh(x) = 1 - 2/(e^{2x}+1), clamped to avoid inf/inf
    float xc = fminf(fmaxf(x, -15.0f), 15.0f);
    float e = __expf(2.0f * xc);
    return 1.0f - 2.0f * frcp(e + 1.0f);
}

__global__ __launch_bounds__(256) void lstm4_kernel(
    const float* __restrict__ input,
    const float* __restrict__ w_ih1, const float* __restrict__ w_hh1,
    const float* __restrict__ b_ih1, const float* __restrict__ b_hh1,
    const float* __restrict__ w_ih2, const float* __restrict__ w_hh2,
    const float* __restrict__ b_ih2, const float* __restrict__ b_hh2,
    const float* __restrict__ w_ih3, const float* __restrict__ w_hh3,
    const float* __restrict__ b_ih3, const float* __restrict__ b_hh3,
    const float* __restrict__ w_ih4, const float* __restrict__ w_hh4,
    const float* __restrict__ b_ih4, const float* __restrict__ b_hh4,
    float* __restrict__ out)
{
    const int lane = threadIdx.x & 63;
    const int b    = blockIdx.x * 4 + (threadIdx.x >> 6);
    const bool act = lane < H;
    const int  k   = act ? lane : (H - 1);  // clamped for safe addressing

    // Hoisted per-lane constants
    float bias1[4], bias2[4], bias3[4], wih1[4], wih4[4], bias4[4], whh4[4];
#pragma unroll
    for (int q = 0; q < 4; ++q) {
        const int r = q * H + k;
        bias1[q] = b_ih1[r] + b_hh1[r];
        bias2[q] = b_ih2[r] + b_hh2[r];
        bias3[q] = b_ih3[r] + b_hh3[r];
        wih1[q]  = w_ih1[r];                       // (204,1)
        wih4[q]  = act ? w_ih4[q * H + k] : 0.0f;  // (4,51), masked for idle lanes
        bias4[q] = b_ih4[q] + b_hh4[q];
        whh4[q]  = w_hh4[q];                       // (4,1)
    }

    // Row base offsets for this lane's 4 gate rows in each 204x51 matrix
    size_t row[4];
#pragma unroll
    for (int q = 0; q < 4; ++q) row[q] = (size_t)(q * H + k) * H;

    float h1 = 0.f, c1 = 0.f, h2 = 0.f, c2 = 0.f;
    float h3 = 0.f, c3 = 0.f, h4 = 0.f, c4 = 0.f;

    for (int t = 0; t <= T_STEPS; ++t) {
        // Extra feedback step at t == T: x = current c4
        const float x = (t < T_STEPS) ? input[(size_t)b * T_STEPS + t] : c4;

        // ---------------- layer 1: gates = x*w_ih1 + h1 @ w_hh1^T + b ----------
        float a[4];
#pragma unroll
        for (int q = 0; q < 4; ++q) a[q] = fmaf(wih1[q], x, bias1[q]);
#pragma unroll 4
        for (int j = 0; j < H; ++j) {
            const float hj = __shfl(h1, j);
#pragma unroll
            for (int q = 0; q < 4; ++q)
                a[q] = fmaf(w_hh1[row[q] + j], hj, a[q]);
        }
        {
            const float i_ = sigmoid_f(a[0]), f_ = sigmoid_f(a[1]);
            const float g_ = tanh_f(a[2]),    o_ = sigmoid_f(a[3]);
            const float cn = f_ * c1 + i_ * g_;
            c1 = act ? cn : 0.f;
            h1 = act ? o_ * tanh_f(cn) : 0.f;
        }

        // ---------------- layer 2: input is c1 ---------------------------------
#pragma unroll
        for (int q = 0; q < 4; ++q) a[q] = bias2[q];
#pragma unroll 4
        for (int j = 0; j < H; ++j) {
            const float xj = __shfl(c1, j);
            const float hj = __shfl(h2, j);
#pragma unroll
            for (int q = 0; q < 4; ++q) {
                a[q] = fmaf(w_ih2[row[q] + j], xj, a[q]);
                a[q] = fmaf(w_hh2[row[q] + j], hj, a[q]);
            }
        }
        {
            const float i_ = sigmoid_f(a[0]), f_ = sigmoid_f(a[1]);
            const float g_ = tanh_f(a[2]),    o_ = sigmoid_f(a[3]);
            const float cn = f_ * c2 + i_ * g_;
            c2 = act ? cn : 0.f;
            h2 = act ? o_ * tanh_f(cn) : 0.f;
        }

        // ---------------- layer 3: input is c2 ---------------------------------
#pragma unroll
        for (int q = 0; q < 4; ++q) a[q] = bias3[q];
#pragma unroll 4
        for (int j = 0; j < H; ++j) {
            const float xj = __shfl(c2, j);
            const float hj = __shfl(h3, j);
#pragma unroll
            for (int q = 0; q < 4; ++q) {
                a[q] = fmaf(w_ih3[row[q] + j], xj, a[q]);
                a[q] = fmaf(w_hh3[row[q] + j], hj, a[q]);
            }
        }
        {
            const float i_ = sigmoid_f(a[0]), f_ = sigmoid_f(a[1]);
            const float g_ = tanh_f(a[2]),    o_ = sigmoid_f(a[3]);
            const float cn = f_ * c3 + i_ * g_;
            c3 = act ? cn : 0.f;
            h3 = act ? o_ * tanh_f(cn) : 0.f;
        }

        // ---------------- layer 4: input is c3, hidden size 1 -------------------
        float p[4];
#pragma unroll
        for (int q = 0; q < 4; ++q) p[q] = wih4[q] * c3;  // idle lanes contribute 0
#pragma unroll
        for (int m = 1; m < 64; m <<= 1) {
#pragma unroll
            for (int q = 0; q < 4; ++q) p[q] += __shfl_xor(p[q], m);
        }
        {
            const float i_ = sigmoid_f(p[0] + bias4[0] + whh4[0] * h4);
            const float f_ = sigmoid_f(p[1] + bias4[1] + whh4[1] * h4);
            const float g_ = tanh_f  (p[2] + bias4[2] + whh4[2] * h4);
            const float o_ = sigmoid_f(p[3] + bias4[3] + whh4[3] * h4);
            c4 = f_ * c4 + i_ * g_;
            h4 = o_ * tanh_f(c4);
        }
    }

    if (lane == 0) out[b] = c4;
}

extern "C" void kernel_launch(void* const* d_in, const int* in_sizes, int n_in,
                              void* d_out, int out_size, void* d_ws, size_t ws_size,
                              hipStream_t stream) {
    const float* input = (const float*)d_in[0];
    const float* w_ih1 = (const float*)d_in[1];
    const float* w_hh1 = (const float*)d_in[2];
    const float* b_ih1 = (const float*)d_in[3];
    const float* b_hh1 = (const float*)d_in[4];
    const float* w_ih2 = (const float*)d_in[5];
    const float* w_hh2 = (const float*)d_in[6];
    const float* b_ih2 = (const float*)d_in[7];
    const float* b_hh2 = (const float*)d_in[8];
    const float* w_ih3 = (const float*)d_in[9];
    const float* w_hh3 = (const float*)d_in[10];
    const float* b_ih3 = (const float*)d_in[11];
    const float* b_hh3 = (const float*)d_in[12];
    const float* w_ih4 = (const float*)d_in[13];
    const float* w_hh4 = (const float*)d_in[14];
    const float* b_ih4 = (const float*)d_in[15];
    const float* b_hh4 = (const float*)d_in[16];

    dim3 grid(BATCH / 4);   // 512 workgroups, 4 waves each = 2048 waves (1 per batch elem)
    dim3 block(256);
    hipLaunchKernelGGL(lstm4_kernel, grid, block, 0, stream,
                       input,
                       w_ih1, w_hh1, b_ih1, b_hh1,
                       w_ih2, w_hh2, b_ih2, b_hh2,
                       w_ih3, w_hh3, b_ih3, b_hh3,
                       w_ih4, w_hh4, b_ih4, b_hh4,
                       (float*)d_out);
}

// Round 2
// 2644.725 us; speedup vs baseline: 5.8959x; 5.8959x over previous
//
#include <hip/hip_runtime.h>

// Round 2: coalesced packed weights (prep kernel -> d_ws), NB=2 batch per wave,
// LDS-staged h/c broadcast vectors (wave-private), 256 WGs x 4 waves with one
// barrier per step for L1 weight-stream sharing.

constexpr int BATCH   = 2048;
constexpr int T_STEPS = 256;
constexpr int H       = 51;    // hidden size, layers 1-3
constexpr int G4      = 204;   // 4*H gate rows
constexpr int WPM     = H * G4; // floats per packed matrix = 10404

__device__ __forceinline__ float frcp(float x) {
#if __has_builtin(__builtin_amdgcn_rcpf)
    return __builtin_amdgcn_rcpf(x);
#else
    return 1.0f / x;
#endif
}

__device__ __forceinline__ float sigmoid_f(float x) {
    float e = __expf(-x);
    return frcp(1.0f + e);
}

__device__ __forceinline__ float tanh_f(float x) {
    float xc = fminf(fmaxf(x, -15.0f), 15.0f);
    float e = __expf(2.0f * xc);
    return 1.0f - 2.0f * frcp(e + 1.0f);
}

// Pack: wp[m][j][4k+q] = Wm[q*H+k][j]   (m = w_hh1, w_ih2, w_hh2, w_ih3, w_hh3)
__global__ __launch_bounds__(256) void prep_kernel(
    const float* __restrict__ w_hh1, const float* __restrict__ w_ih2,
    const float* __restrict__ w_hh2, const float* __restrict__ w_ih3,
    const float* __restrict__ w_hh3, float* __restrict__ wp)
{
    int idx = blockIdx.x * 256 + threadIdx.x;
    if (idx >= 5 * WPM) return;
    int m   = idx / WPM, rem = idx % WPM;
    int j   = rem / G4,  rp  = rem % G4;
    int k   = rp >> 2,   q   = rp & 3;
    const float* W = (m == 0) ? w_hh1 : (m == 1) ? w_ih2 : (m == 2) ? w_hh2
                   : (m == 3) ? w_ih3 : w_hh3;
    wp[idx] = W[(q * H + k) * H + j];
}

__global__ __launch_bounds__(256) void lstm4_main(
    const float* __restrict__ input, const float* __restrict__ wp,
    const float* __restrict__ w_ih1,
    const float* __restrict__ b_ih1, const float* __restrict__ b_hh1,
    const float* __restrict__ b_ih2, const float* __restrict__ b_hh2,
    const float* __restrict__ b_ih3, const float* __restrict__ b_hh3,
    const float* __restrict__ w_ih4, const float* __restrict__ w_hh4,
    const float* __restrict__ b_ih4, const float* __restrict__ b_hh4,
    float* __restrict__ out)
{
    // Wave-private staging: sv[wave][vec][j][nb]; vec: 0=h1 1=c1 2=h2 3=c2 4=h3
    __shared__ float sv[4][5][H][2];

    const int lane = threadIdx.x & 63;
    const int wv   = threadIdx.x >> 6;
    const int gw   = blockIdx.x * 4 + wv;   // global wave id, 0..1023
    const int b0   = gw * 2, b1 = b0 + 1;
    const bool act = lane < H;
    const int  k   = act ? lane : (H - 1);

    // Hoisted per-lane constants
    float bias1[4], bias2[4], bias3[4], wih1[4], wih4[4], bias4[4], whh4[4];
#pragma unroll
    for (int q = 0; q < 4; ++q) {
        const int r = q * H + k;
        bias1[q] = b_ih1[r] + b_hh1[r];
        bias2[q] = b_ih2[r] + b_hh2[r];
        bias3[q] = b_ih3[r] + b_hh3[r];
        wih1[q]  = w_ih1[r];
        wih4[q]  = act ? w_ih4[q * H + k] : 0.0f;
        bias4[q] = b_ih4[q] + b_hh4[q];
        whh4[q]  = w_hh4[q];
    }

    // Per-lane packed weight base pointers (lane reads float4 at [j][4k])
    const float* pw0 = wp + 0 * WPM + 4 * k;  // w_hh1
    const float* pw1 = wp + 1 * WPM + 4 * k;  // w_ih2
    const float* pw2 = wp + 2 * WPM + 4 * k;  // w_hh2
    const float* pw3 = wp + 3 * WPM + 4 * k;  // w_ih3
    const float* pw4 = wp + 4 * WPM + 4 * k;  // w_hh3

    float* svw = &sv[wv][0][0][0];  // this wave's slice; vec v at offset v*H*2

    // init states
    float h1_0=0.f,h1_1=0.f,c1_0=0.f,c1_1=0.f;
    float h2_0=0.f,h2_1=0.f,c2_0=0.f,c2_1=0.f;
    float h3_0=0.f,h3_1=0.f,c3_0=0.f,c3_1=0.f;
    float h4_0=0.f,h4_1=0.f,c4_0=0.f,c4_1=0.f;

    if (act) {
#pragma unroll
        for (int v = 0; v < 5; ++v) {
            svw[v * H * 2 + k * 2 + 0] = 0.f;
            svw[v * H * 2 + k * 2 + 1] = 0.f;
        }
    }
    __syncthreads();

    for (int t = 0; t <= T_STEPS; ++t) {
        __syncthreads();  // keep the 4 waves aligned for L1 weight-stream reuse
        const float x0 = (t < T_STEPS) ? input[(size_t)b0 * T_STEPS + t] : c4_0;
        const float x1 = (t < T_STEPS) ? input[(size_t)b1 * T_STEPS + t] : c4_1;

        // ---------------- layer 1 ----------------
        float a0[4], a1[4];
#pragma unroll
        for (int q = 0; q < 4; ++q) {
            a0[q] = fmaf(wih1[q], x0, bias1[q]);
            a1[q] = fmaf(wih1[q], x1, bias1[q]);
        }
#pragma unroll 3
        for (int j = 0; j < H; ++j) {
            const float4 wq = *(const float4*)(pw0 + (size_t)j * G4);
            const float2 hv = *(const float2*)(svw + 0 * H * 2 + j * 2);
            a0[0] = fmaf(wq.x, hv.x, a0[0]); a1[0] = fmaf(wq.x, hv.y, a1[0]);
            a0[1] = fmaf(wq.y, hv.x, a0[1]); a1[1] = fmaf(wq.y, hv.y, a1[1]);
            a0[2] = fmaf(wq.z, hv.x, a0[2]); a1[2] = fmaf(wq.z, hv.y, a1[2]);
            a0[3] = fmaf(wq.w, hv.x, a0[3]); a1[3] = fmaf(wq.w, hv.y, a1[3]);
        }
        {
            float i0=sigmoid_f(a0[0]), f0=sigmoid_f(a0[1]), g0=tanh_f(a0[2]), o0=sigmoid_f(a0[3]);
            float i1=sigmoid_f(a1[0]), f1=sigmoid_f(a1[1]), g1=tanh_f(a1[2]), o1=sigmoid_f(a1[3]);
            c1_0 = f0*c1_0 + i0*g0;  h1_0 = o0*tanh_f(c1_0);
            c1_1 = f1*c1_1 + i1*g1;  h1_1 = o1*tanh_f(c1_1);
        }
        if (act) {
            svw[0*H*2 + k*2 + 0] = h1_0;  svw[0*H*2 + k*2 + 1] = h1_1;  // for next step
            svw[1*H*2 + k*2 + 0] = c1_0;  svw[1*H*2 + k*2 + 1] = c1_1;  // layer-2 input now
        }

        // ---------------- layer 2 (input = c1) ----------------
#pragma unroll
        for (int q = 0; q < 4; ++q) { a0[q] = bias2[q]; a1[q] = bias2[q]; }
#pragma unroll 3
        for (int j = 0; j < H; ++j) {
            const float4 wi = *(const float4*)(pw1 + (size_t)j * G4);
            const float4 wh = *(const float4*)(pw2 + (size_t)j * G4);
            const float2 xv = *(const float2*)(svw + 1 * H * 2 + j * 2);
            const float2 hv = *(const float2*)(svw + 2 * H * 2 + j * 2);
            a0[0]=fmaf(wi.x,xv.x,a0[0]); a1[0]=fmaf(wi.x,xv.y,a1[0]);
            a0[1]=fmaf(wi.y,xv.x,a0[1]); a1[1]=fmaf(wi.y,xv.y,a1[1]);
            a0[2]=fmaf(wi.z,xv.x,a0[2]); a1[2]=fmaf(wi.z,xv.y,a1[2]);
            a0[3]=fmaf(wi.w,xv.x,a0[3]); a1[3]=fmaf(wi.w,xv.y,a1[3]);
            a0[0]=fmaf(wh.x,hv.x,a0[0]); a1[0]=fmaf(wh.x,hv.y,a1[0]);
            a0[1]=fmaf(wh.y,hv.x,a0[1]); a1[1]=fmaf(wh.y,hv.y,a1[1]);
            a0[2]=fmaf(wh.z,hv.x,a0[2]); a1[2]=fmaf(wh.z,hv.y,a1[2]);
            a0[3]=fmaf(wh.w,hv.x,a0[3]); a1[3]=fmaf(wh.w,hv.y,a1[3]);
        }
        {
            float i0=sigmoid_f(a0[0]), f0=sigmoid_f(a0[1]), g0=tanh_f(a0[2]), o0=sigmoid_f(a0[3]);
            float i1=sigmoid_f(a1[0]), f1=sigmoid_f(a1[1]), g1=tanh_f(a1[2]), o1=sigmoid_f(a1[3]);
            c2_0 = f0*c2_0 + i0*g0;  h2_0 = o0*tanh_f(c2_0);
            c2_1 = f1*c2_1 + i1*g1;  h2_1 = o1*tanh_f(c2_1);
        }
        if (act) {
            svw[2*H*2 + k*2 + 0] = h2_0;  svw[2*H*2 + k*2 + 1] = h2_1;  // next step
            svw[3*H*2 + k*2 + 0] = c2_0;  svw[3*H*2 + k*2 + 1] = c2_1;  // layer-3 input now
        }

        // ---------------- layer 3 (input = c2) ----------------
#pragma unroll
        for (int q = 0; q < 4; ++q) { a0[q] = bias3[q]; a1[q] = bias3[q]; }
#pragma unroll 3
        for (int j = 0; j < H; ++j) {
            const float4 wi = *(const float4*)(pw3 + (size_t)j * G4);
            const float4 wh = *(const float4*)(pw4 + (size_t)j * G4);
            const float2 xv = *(const float2*)(svw + 3 * H * 2 + j * 2);
            const float2 hv = *(const float2*)(svw + 4 * H * 2 + j * 2);
            a0[0]=fmaf(wi.x,xv.x,a0[0]); a1[0]=fmaf(wi.x,xv.y,a1[0]);
            a0[1]=fmaf(wi.y,xv.x,a0[1]); a1[1]=fmaf(wi.y,xv.y,a1[1]);
            a0[2]=fmaf(wi.z,xv.x,a0[2]); a1[2]=fmaf(wi.z,xv.y,a1[2]);
            a0[3]=fmaf(wi.w,xv.x,a0[3]); a1[3]=fmaf(wi.w,xv.y,a1[3]);
            a0[0]=fmaf(wh.x,hv.x,a0[0]); a1[0]=fmaf(wh.x,hv.y,a1[0]);
            a0[1]=fmaf(wh.y,hv.x,a0[1]); a1[1]=fmaf(wh.y,hv.y,a1[1]);
            a0[2]=fmaf(wh.z,hv.x,a0[2]); a1[2]=fmaf(wh.z,hv.y,a1[2]);
            a0[3]=fmaf(wh.w,hv.x,a0[3]); a1[3]=fmaf(wh.w,hv.y,a1[3]);
        }
        {
            float i0=sigmoid_f(a0[0]), f0=sigmoid_f(a0[1]), g0=tanh_f(a0[2]), o0=sigmoid_f(a0[3]);
            float i1=sigmoid_f(a1[0]), f1=sigmoid_f(a1[1]), g1=tanh_f(a1[2]), o1=sigmoid_f(a1[3]);
            c3_0 = f0*c3_0 + i0*g0;  h3_0 = o0*tanh_f(c3_0);
            c3_1 = f1*c3_1 + i1*g1;  h3_1 = o1*tanh_f(c3_1);
        }
        if (act) {
            svw[4*H*2 + k*2 + 0] = h3_0;  svw[4*H*2 + k*2 + 1] = h3_1;  // next step
        }

        // ---------------- layer 4 (input = c3, hidden 1) ----------------
        float p0[4], p1[4];
#pragma unroll
        for (int q = 0; q < 4; ++q) { p0[q] = wih4[q] * c3_0; p1[q] = wih4[q] * c3_1; }
#pragma unroll
        for (int m = 1; m < 64; m <<= 1) {
#pragma unroll
            for (int q = 0; q < 4; ++q) {
                p0[q] += __shfl_xor(p0[q], m);
                p1[q] += __shfl_xor(p1[q], m);
            }
        }
        {
            float i0=sigmoid_f(p0[0]+bias4[0]+whh4[0]*h4_0);
            float f0=sigmoid_f(p0[1]+bias4[1]+whh4[1]*h4_0);
            float g0=tanh_f  (p0[2]+bias4[2]+whh4[2]*h4_0);
            float o0=sigmoid_f(p0[3]+bias4[3]+whh4[3]*h4_0);
            c4_0 = f0*c4_0 + i0*g0;  h4_0 = o0*tanh_f(c4_0);
            float i1=sigmoid_f(p1[0]+bias4[0]+whh4[0]*h4_1);
            float f1=sigmoid_f(p1[1]+bias4[1]+whh4[1]*h4_1);
            float g1=tanh_f  (p1[2]+bias4[2]+whh4[2]*h4_1);
            float o1=sigmoid_f(p1[3]+bias4[3]+whh4[3]*h4_1);
            c4_1 = f1*c4_1 + i1*g1;  h4_1 = o1*tanh_f(c4_1);
        }
    }

    if (lane == 0) { out[b0] = c4_0; out[b1] = c4_1; }
}

extern "C" void kernel_launch(void* const* d_in, const int* in_sizes, int n_in,
                              void* d_out, int out_size, void* d_ws, size_t ws_size,
                              hipStream_t stream) {
    const float* input = (const float*)d_in[0];
    const float* w_ih1 = (const float*)d_in[1];
    const float* w_hh1 = (const float*)d_in[2];
    const float* b_ih1 = (const float*)d_in[3];
    const float* b_hh1 = (const float*)d_in[4];
    const float* w_ih2 = (const float*)d_in[5];
    const float* w_hh2 = (const float*)d_in[6];
    const float* b_ih2 = (const float*)d_in[7];
    const float* b_hh2 = (const float*)d_in[8];
    const float* w_ih3 = (const float*)d_in[9];
    const float* w_hh3 = (const float*)d_in[10];
    const float* b_ih3 = (const float*)d_in[11];
    const float* b_hh3 = (const float*)d_in[12];
    const float* w_ih4 = (const float*)d_in[13];
    const float* w_hh4 = (const float*)d_in[14];
    const float* b_ih4 = (const float*)d_in[15];
    const float* b_hh4 = (const float*)d_in[16];

    float* wp = (float*)d_ws;  // 5*WPM*4 = 208,080 bytes

    hipLaunchKernelGGL(prep_kernel, dim3((5 * WPM + 255) / 256), dim3(256), 0, stream,
                       w_hh1, w_ih2, w_hh2, w_ih3, w_hh3, wp);

    hipLaunchKernelGGL(lstm4_main, dim3(BATCH / 8), dim3(256), 0, stream,
                       input, wp, w_ih1,
                       b_ih1, b_hh1, b_ih2, b_hh2, b_ih3, b_hh3,
                       w_ih4, w_hh4, b_ih4, b_hh4,
                       (float*)d_out);
}